// Round 6
// baseline (22950.558 us; speedup 1.0000x reference)
//
#include <hip/hip_runtime.h>
#include <hip/hip_bf16.h>
#include <math.h>

// PRNN persistent kernel, round 6: 32x8 skeleton; decoder lagged 2 steps (4-slot hb
// ring) and moved off the critical path (no wait/acquire needed — covered by the
// phase-A release/acquire chain). Critical path per step: wait chunk flags -> GEMM
// -> partial store -> ctr release -> ctr wait -> combine+gate -> flag release.
// Exactly 2 rendezvous / 2 cache-invalidates per step.
// y_t = h_t @ Wdec^T + b_dec ; h_t = (1-s)h_{t-1} + s*a*tanh(x_t@Wenc^T + b_enc + h_{t-1}@Wrec^T + b_rec)

#define B_   256
#define T_   512
#define NI_  512
#define NH_  2048
#define NO_  256

#define NCB  32          // col groups (64 cols each)
#define NKB  8           // K slices (320 each, composite K = 2560)
#define KW   320
#define NCHUNK 5         // 5 x 64-K chunks per slice

typedef __bf16 bf16_t;
typedef __bf16 bf16x8 __attribute__((ext_vector_type(8)));
typedef float  f32x4  __attribute__((ext_vector_type(4)));

#define MFMA16(a,b,c) __builtin_amdgcn_mfma_f32_16x16x32_bf16((a),(b),(c),0,0,0)

__device__ __forceinline__ void nt_store_f(float v, float* p) {
  __builtin_nontemporal_store(v, p);
}
__device__ __forceinline__ void nt_store_v4(f32x4 v, float* p) {
  __builtin_nontemporal_store(v, reinterpret_cast<f32x4*>(p));
}

__global__ __launch_bounds__(256) void k_cvt(const float* __restrict__ src,
                                             bf16_t* __restrict__ dst, int n) {
  int i = blockIdx.x * 256 + threadIdx.x;
  const int stride = gridDim.x * 256;
  for (; i < n; i += stride) dst[i] = (bf16_t)src[i];
}

__device__ __forceinline__ void spin_ge(int* p, int target) {
  while (__hip_atomic_load(p, __ATOMIC_RELAXED, __HIP_MEMORY_SCOPE_AGENT) < target)
    __builtin_amdgcn_s_sleep(2);
  (void)__hip_atomic_load(p, __ATOMIC_ACQUIRE, __HIP_MEMORY_SCOPE_AGENT);
}

// One 16x16 tile of y = h @ Wdec^T + b_dec per WG (K=2048 split over 4 waves).
__device__ __forceinline__ void dec_tile(int wgid, int tid,
    const bf16_t* __restrict__ hbp, const bf16_t* __restrict__ Wdec,
    const float* __restrict__ b_dec, float* __restrict__ y_out, float* Ds) {
  const int lane = tid & 63;
  const int wv2 = tid >> 6;
  const int fl = lane & 15;
  const int kg = lane >> 4;
  const int dr = (wgid >> 4) * 16;
  const int dc = (wgid & 15) * 16;
  f32x4 dacc = {0.f, 0.f, 0.f, 0.f};
  const int kw = wv2 * 512;
  #pragma unroll 4
  for (int ks = 0; ks < 16; ++ks) {
    const int k = kw + ks * 32 + kg * 8;
    bf16x8 af = *reinterpret_cast<const bf16x8*>(hbp + (size_t)(dr + fl) * NH_ + k);
    bf16x8 bf = *reinterpret_cast<const bf16x8*>(Wdec + (size_t)(dc + fl) * NH_ + k);
    dacc = MFMA16(af, bf, dacc);
  }
  __syncthreads();
  #pragma unroll
  for (int j = 0; j < 4; ++j)
    Ds[wv2 * 256 + (kg * 4 + j) * 16 + fl] = dacc[j];
  __syncthreads();
  const int er = tid >> 4, ec = tid & 15;
  const float yv = Ds[er * 16 + ec] + Ds[256 + er * 16 + ec] + Ds[512 + er * 16 + ec] +
                   Ds[768 + er * 16 + ec] + b_dec[dc + ec];
  nt_store_f(yv, &y_out[(size_t)(dr + er) * NO_ + (dc + ec)]);
}

__global__ __launch_bounds__(256, 1) void k_prnn(
    const float* __restrict__ x,
    const float* __restrict__ dt_p, const float* __restrict__ a_p,
    const float* __restrict__ Wrec, const float* __restrict__ Wenc,
    const bf16_t* __restrict__ Wdec,
    const float* __restrict__ b_rec, const float* __restrict__ b_enc,
    const float* __restrict__ b_dec,
    bf16_t* __restrict__ hb,          // 4 ring slots of [B, NH] bf16
    float* __restrict__ partial, int* __restrict__ sync_,
    float* __restrict__ out)
{
  __shared__ alignas(16) bf16x8 Wl[64 * 40];      // 40KB  W slice, LDS-resident
  __shared__ alignas(16) bf16x8 Abuf[2 * 2048];   // 64KB  A double-buffer
  float* Ds = reinterpret_cast<float*>(Abuf);     // 4KB decoder scratch (Abuf dead then)

  const int tid  = threadIdx.x;
  const int lane = tid & 63;
  const int wv   = tid >> 6;
  const int fl   = lane & 15;
  const int kg   = lane >> 4;
  const int bid  = blockIdx.x;
  const int cb   = bid & 31;   // col group
  const int kb   = bid >> 5;   // K slice
  int* flags = sync_;          // flag[cb] at [cb*16]  (64B strided)
  int* ctrs  = sync_ + 512;    // counter[cb] at [512 + cb*16]

  const float sgate = 1.f / (1.f + expf(-dt_p[0]));
  const float av = a_p[0];
  const float gi = 1.f - sgate;

  // f32 master h state: row = tid, cols = cb*64 + kb*8 + 0..8 (same owner every step)
  float hr[8];
  #pragma unroll
  for (int i = 0; i < 8; ++i) hr[i] = 0.f;

  // ---- prologue: load W slice (cols cb*64..+64, composite k kb*320..+320) into LDS
  {
    const int c = tid >> 2;             // 0..63 (local col)
    const int c_g = cb * 64 + c;
    const int sub = tid & 3;
    #pragma unroll
    for (int i = 0; i < 10; ++i) {
      const int gW = sub + 4 * i;       // 0..39
      const int k = kb * KW + gW * 8;
      const float* src = (k < NH_) ? (Wrec + (size_t)c_g * NH_ + k)
                                   : (Wenc + (size_t)c_g * NI_ + (k - NH_));
      float4 f0 = reinterpret_cast<const float4*>(src)[0];
      float4 f1 = reinterpret_cast<const float4*>(src)[1];
      bf16x8 w8 = {(bf16_t)f0.x, (bf16_t)f0.y, (bf16_t)f0.z, (bf16_t)f0.w,
                   (bf16_t)f1.x, (bf16_t)f1.y, (bf16_t)f1.z, (bf16_t)f1.w};
      Wl[c * 40 + (gW ^ (c & 7))] = w8;
    }
  }
  __syncthreads();

  // chunk-wait set for this slice (h chunks are 64-col groups)
  int wfirst = 0, wcount = 0;
  if (kb <= 5)      { wfirst = kb * 5; wcount = 5; }
  else if (kb == 6) { wfirst = 30;     wcount = 2; }

  for (int t = 0; t < T_; ++t) {
    // hb ring: state S_{t-1} (input) in slot t&3; S_t (output) into slot (t+1)&3.
    const bf16_t* hb_in  = hb + (size_t)(t & 3) * B_ * NH_;
    bf16_t*       hb_out = hb + (size_t)((t + 1) & 3) * B_ * NH_;

    // ---- phase A: one batched wait — chunk flags >= 8t (h(t-1) ready) and
    //      flag[cb] >= 8t (partial slot reuse guard). Single trailing acquire.
    if (tid <= wcount) {
      const int idx = (tid < wcount) ? (wfirst + tid) : cb;
      spin_ge(flags + idx * 16, 8 * t);
    }
    __syncthreads();

    // ---- phase B: GEMM acc[256 x 64] over K=320, 5 double-buffered 64-K chunks
    f32x4 acc[4][4];
    #pragma unroll
    for (int i = 0; i < 4; ++i)
      #pragma unroll
      for (int j = 0; j < 4; ++j) acc[i][j] = f32x4{0.f, 0.f, 0.f, 0.f};

    bf16x8 sh[8];
    float4 sx[16];
    bool cx = false;
    auto load_chunk = [&](int c) {
      const int k0 = kb * KW + c * 64;
      cx = (k0 >= NH_);
      if (!cx) {
        const bf16x8* src = reinterpret_cast<const bf16x8*>(hb_in + (size_t)tid * NH_ + k0);
        #pragma unroll
        for (int g = 0; g < 8; ++g) sh[g] = src[g];
      } else {
        const float4* src = reinterpret_cast<const float4*>(
            x + ((size_t)tid * T_ + t) * NI_ + (k0 - NH_));
        #pragma unroll
        for (int q = 0; q < 16; ++q) sx[q] = src[q];
      }
    };

    load_chunk(0);
    #pragma unroll 1
    for (int c = 0; c < NCHUNK; ++c) {
      bf16x8* Ab = Abuf + (c & 1) * 2048;
      __syncthreads();
      if (!cx) {
        #pragma unroll
        for (int g = 0; g < 8; ++g) Ab[tid * 8 + (g ^ (tid & 7))] = sh[g];
      } else {
        #pragma unroll
        for (int g = 0; g < 8; ++g) {
          float4 u = sx[2 * g], v2 = sx[2 * g + 1];
          bf16x8 w8 = {(bf16_t)u.x, (bf16_t)u.y, (bf16_t)u.z, (bf16_t)u.w,
                       (bf16_t)v2.x, (bf16_t)v2.y, (bf16_t)v2.z, (bf16_t)v2.w};
          Ab[tid * 8 + (g ^ (tid & 7))] = w8;
        }
      }
      __syncthreads();
      if (c + 1 < NCHUNK) load_chunk(c + 1);   // prefetch overlaps MFMA below
      #pragma unroll
      for (int ks = 0; ks < 2; ++ks) {
        const int sA = (ks * 4 + kg) ^ (fl & 7);
        const int sW = (c * 8 + ks * 4 + kg) ^ (fl & 7);
        bf16x8 a0 = Ab[(wv * 64 +  0 + fl) * 8 + sA];
        bf16x8 a1 = Ab[(wv * 64 + 16 + fl) * 8 + sA];
        bf16x8 a2 = Ab[(wv * 64 + 32 + fl) * 8 + sA];
        bf16x8 a3 = Ab[(wv * 64 + 48 + fl) * 8 + sA];
        bf16x8 b0 = Wl[( 0 + fl) * 40 + sW];
        bf16x8 b1 = Wl[(16 + fl) * 40 + sW];
        bf16x8 b2 = Wl[(32 + fl) * 40 + sW];
        bf16x8 b3 = Wl[(48 + fl) * 40 + sW];
        acc[0][0] = MFMA16(a0, b0, acc[0][0]);
        acc[0][1] = MFMA16(a0, b1, acc[0][1]);
        acc[0][2] = MFMA16(a0, b2, acc[0][2]);
        acc[0][3] = MFMA16(a0, b3, acc[0][3]);
        acc[1][0] = MFMA16(a1, b0, acc[1][0]);
        acc[1][1] = MFMA16(a1, b1, acc[1][1]);
        acc[1][2] = MFMA16(a1, b2, acc[1][2]);
        acc[1][3] = MFMA16(a1, b3, acc[1][3]);
        acc[2][0] = MFMA16(a2, b0, acc[2][0]);
        acc[2][1] = MFMA16(a2, b1, acc[2][1]);
        acc[2][2] = MFMA16(a2, b2, acc[2][2]);
        acc[2][3] = MFMA16(a2, b3, acc[2][3]);
        acc[3][0] = MFMA16(a3, b0, acc[3][0]);
        acc[3][1] = MFMA16(a3, b1, acc[3][1]);
        acc[3][2] = MFMA16(a3, b2, acc[3][2]);
        acc[3][3] = MFMA16(a3, b3, acc[3][3]);
      }
    }

    // ---- phase C: store f32 partial (NT), drain, ctr release
    {
      float* ps = partial + ((size_t)cb * NKB + kb) * 16384;
      #pragma unroll
      for (int i = 0; i < 4; ++i)
        #pragma unroll
        for (int j = 0; j < 4; ++j)
          #pragma unroll
          for (int jj = 0; jj < 4; ++jj)
            nt_store_f(acc[i][j][jj],
                       &ps[(wv * 64 + i * 16 + kg * 4 + jj) * 64 + (j * 16 + fl)]);
    }
    __syncthreads();   // drains vmcnt before the release below
    if (tid == 0)
      __hip_atomic_fetch_add(ctrs + cb * 16, 1, __ATOMIC_RELEASE, __HIP_MEMORY_SCOPE_AGENT);

    // ---- phase D: wait all 8 slices of my group, combine cols [cb*64+kb*8, +8),
    //      gate with register master state, write hb_out chunk, release flag
    if (tid == 0) spin_ge(ctrs + cb * 16, 8 * (t + 1));
    __syncthreads();
    {
      const float* pb = partial + (size_t)cb * NKB * 16384;
      const int r = tid;
      const int jc = kb * 8;
      float v0 = 0.f, v1 = 0.f, v2 = 0.f, v3 = 0.f, v4 = 0.f, v5 = 0.f, v6 = 0.f, v7 = 0.f;
      #pragma unroll
      for (int kk = 0; kk < NKB; ++kk) {
        const float4* row = reinterpret_cast<const float4*>(pb + (size_t)kk * 16384 + r * 64 + jc);
        float4 u = row[0], w = row[1];
        v0 += u.x; v1 += u.y; v2 += u.z; v3 += u.w;
        v4 += w.x; v5 += w.y; v6 += w.z; v7 += w.w;
      }
      const int cg = cb * 64 + jc;
      float4 br0 = *reinterpret_cast<const float4*>(b_rec + cg);
      float4 br1 = *reinterpret_cast<const float4*>(b_rec + cg + 4);
      float4 be0 = *reinterpret_cast<const float4*>(b_enc + cg);
      float4 be1 = *reinterpret_cast<const float4*>(b_enc + cg + 4);
      f32x4 o0, o1;
      o0[0] = gi * hr[0] + sgate * av * tanhf(v0 + br0.x + be0.x);
      o0[1] = gi * hr[1] + sgate * av * tanhf(v1 + br0.y + be0.y);
      o0[2] = gi * hr[2] + sgate * av * tanhf(v2 + br0.z + be0.z);
      o0[3] = gi * hr[3] + sgate * av * tanhf(v3 + br0.w + be0.w);
      o1[0] = gi * hr[4] + sgate * av * tanhf(v4 + br1.x + be1.x);
      o1[1] = gi * hr[5] + sgate * av * tanhf(v5 + br1.y + be1.y);
      o1[2] = gi * hr[6] + sgate * av * tanhf(v6 + br1.z + be1.z);
      o1[3] = gi * hr[7] + sgate * av * tanhf(v7 + br1.w + be1.w);
      hr[0] = o0[0]; hr[1] = o0[1]; hr[2] = o0[2]; hr[3] = o0[3];
      hr[4] = o1[0]; hr[5] = o1[1]; hr[6] = o1[2]; hr[7] = o1[3];
      bf16x8 ob = {(bf16_t)o0[0], (bf16_t)o0[1], (bf16_t)o0[2], (bf16_t)o0[3],
                   (bf16_t)o1[0], (bf16_t)o1[1], (bf16_t)o1[2], (bf16_t)o1[3]};
      f32x4 obv;
      __builtin_memcpy(&obv, &ob, 16);
      nt_store_v4(obv, reinterpret_cast<float*>(hb_out + (size_t)r * NH_ + cg));
      if (t == T_ - 1) {   // exact f32 final h straight from the register master
        nt_store_v4(o0, out + (size_t)T_ * B_ * NO_ + (size_t)r * NH_ + cg);
        nt_store_v4(o1, out + (size_t)T_ * B_ * NO_ + (size_t)r * NH_ + cg + 4);
      }
    }
    __syncthreads();   // drain h stores
    if (tid == 0)
      __hip_atomic_fetch_add(flags + cb * 16, 1, __ATOMIC_RELEASE, __HIP_MEMORY_SCOPE_AGENT);

    // ---- phase E (off critical path): decoder for y_{t-2}, lagged 2 steps.
    // Reads hb slot (t-1)&3 = S_{t-2}. No wait/acquire needed: phase A's acquire at
    // this iter transitively covers all combines(t-2) (release/acquire chaining),
    // and slot (t-1)&3 is next overwritten by combine(t+2), which transitively
    // requires my combine(t+1) — which follows this dec in program order.
    if (t >= 2)
      dec_tile(bid, tid, hb + (size_t)((t - 1) & 3) * B_ * NH_, Wdec, b_dec,
               out + (size_t)(t - 2) * B_ * NO_, Ds);
  }

  // ---- epilogue: y_{T-2} (slot (T-1)&3) and y_{T-1} (slot T&3 = 0), with real waits
  if (tid < 32) spin_ge(flags + tid * 16, 8 * (T_ - 1));
  __syncthreads();
  dec_tile(bid, tid, hb + (size_t)((T_ - 1) & 3) * B_ * NH_, Wdec, b_dec,
           out + (size_t)(T_ - 2) * B_ * NO_, Ds);
  if (tid < 32) spin_ge(flags + tid * 16, 8 * T_);
  __syncthreads();
  dec_tile(bid, tid, hb /* slot 0 = S_{T-1} */, Wdec, b_dec,
           out + (size_t)(T_ - 1) * B_ * NO_, Ds);
}

extern "C" void kernel_launch(void* const* d_in, const int* in_sizes, int n_in,
                              void* d_out, int out_size, void* d_ws, size_t ws_size,
                              hipStream_t stream) {
  const float* x     = (const float*)d_in[0];
  const float* dt_p  = (const float*)d_in[1];
  const float* a_p   = (const float*)d_in[2];
  const float* W_enc = (const float*)d_in[3];
  const float* b_enc = (const float*)d_in[4];
  const float* W_rec = (const float*)d_in[5];
  const float* b_rec = (const float*)d_in[6];
  const float* W_dec = (const float*)d_in[7];
  const float* b_dec = (const float*)d_in[8];
  float* out = (float*)d_out;

  char* p = (char*)d_ws;
  bf16_t* hb      = (bf16_t*)p;  p += 4 * (size_t)B_ * NH_ * 2;        // 4MB (ring of 4)
  bf16_t* Wdec_b  = (bf16_t*)p;  p += (size_t)NO_ * NH_ * 2;           // 1MB
  float*  partial = (float*)p;   p += (size_t)NCB * NKB * 16384 * 4;   // 16MB
  int*    sync_   = (int*)p;     p += 4096;                            // ~21MB total

  hipMemsetAsync(hb, 0, (size_t)B_ * NH_ * 2, stream);   // slot 0 = S_{-1} = 0
  hipMemsetAsync(sync_, 0, 4096, stream);

  k_cvt<<<64, 256, 0, stream>>>(W_dec, Wdec_b, NO_ * NH_);

  k_prnn<<<dim3(256), dim3(256), 0, stream>>>(
      x, dt_p, a_p, W_rec, W_enc, Wdec_b, b_rec, b_enc, b_dec,
      hb, partial, sync_, out);
}